// Round 1
// baseline (192.153 us; speedup 1.0000x reference)
//
#include <hip/hip_runtime.h>
#include <cmath>

#define FDIM 128

// Pack the used columns (3f+1, 3f+2) of Wf and W2 into [k][f] layout so the
// hot loops read them coalesced.
__global__ void pack_w_kernel(const float* __restrict__ Wf, const float* __restrict__ W2,
                              float* __restrict__ Wf1T, float* __restrict__ Wf2T,
                              float* __restrict__ W21T, float* __restrict__ W22T) {
  int k = blockIdx.x;
  int f = threadIdx.x;
  Wf1T[k * FDIM + f] = Wf[k * 3 * FDIM + 3 * f + 1];
  Wf2T[k * FDIM + f] = Wf[k * 3 * FDIM + 3 * f + 2];
  W21T[k * FDIM + f] = W2[k * 3 * FDIM + 3 * f + 1];
  W22T[k * FDIM + f] = W2[k * 3 * FDIM + 3 * f + 2];
}

// phi = silu(h@W1+b1)@W2+b2, keeping only columns 3f+1 (phi1) and 3f+2 (phi2).
__global__ __launch_bounds__(FDIM) void phi_kernel(
    const float* __restrict__ h, const float* __restrict__ W1, const float* __restrict__ b1,
    const float* __restrict__ W21T, const float* __restrict__ W22T, const float* __restrict__ b2,
    float* __restrict__ phi1, float* __restrict__ phi2) {
  __shared__ float hrow[FDIM];
  __shared__ float trow[FDIM];
  const size_t row = blockIdx.x;
  const int f = threadIdx.x;
  hrow[f] = h[row * FDIM + f];
  __syncthreads();
  float acc = b1[f];
#pragma unroll 8
  for (int k = 0; k < FDIM; ++k) acc = fmaf(hrow[k], W1[k * FDIM + f], acc);
  // silu
  trow[f] = acc / (1.0f + __expf(-acc));
  __syncthreads();
  float p1 = b2[3 * f + 1];
  float p2 = b2[3 * f + 2];
#pragma unroll 8
  for (int k = 0; k < FDIM; ++k) {
    const float t = trow[k];
    p1 = fmaf(t, W21T[k * FDIM + f], p1);
    p2 = fmaf(t, W22T[k * FDIM + f], p2);
  }
  phi1[row * FDIM + f] = p1;
  phi2[row * FDIM + f] = p2;
}

// Main fused kernel. Grid: (ASPLIT, NC, B). Each block owns one (b,c) and a
// contiguous chunk of atoms. Per 64-atom tile:
//   G[k][a] = exp(-(d_a - o_k)^2) staged in LDS,
//   S1/S2 = G^T-style register GEMM vs Wf1T/Wf2T (streamed in 16-k LDS chunks),
//   epilogue: dH[f] += (S1+bf1)*phi1,  dV[f,x] += (S2+bf2)*phi2*u_x.
// Partials written per (az, b, c) — deterministic, no float atomics.
template <int ASPLIT>
__global__ __launch_bounds__(256) void enc_main_kernel(
    const float* __restrict__ xyz, const float* __restrict__ cg_xyz,
    const float* __restrict__ Wf1T, const float* __restrict__ Wf2T,
    const float* __restrict__ bf,
    const float* __restrict__ phi1, const float* __restrict__ phi2,
    float* __restrict__ pH, float* __restrict__ pV,
    int NA, int NC, int BNC) {
  constexpr int KC = 16;
  __shared__ float G[FDIM * 64];     // 32 KB  [k][a]
  __shared__ float Wc1[KC * FDIM];   // 8 KB   [kk][f]
  __shared__ float Wc2[KC * FDIM];   // 8 KB
  __shared__ float dl[64];
  __shared__ float ul[64 * 3];
  __shared__ float red[8 * FDIM];    // 4 KB cross-ag reduction buffer

  const int az = blockIdx.x;
  const int c = blockIdx.y;
  const int b = blockIdx.z;
  const int bc = b * NC + c;
  const int tid = threadIdx.x;
  const int ag = tid >> 5;  // atom group 0..7  (8 atoms each)
  const int fg = tid & 31;  // f group 0..31    (4 f each)

  const float cgx = cg_xyz[bc * 3 + 0];
  const float cgy = cg_xyz[bc * 3 + 1];
  const float cgz = cg_xyz[bc * 3 + 2];

  const int APA = (NA + ASPLIT - 1) / ASPLIT;
  const int a0 = az * APA;
  const int a_end = min(NA, a0 + APA);
  const int ntiles = (APA + 63) >> 6;

  float bf1r[4], bf2r[4];
#pragma unroll
  for (int j = 0; j < 4; ++j) {
    const int f = fg * 4 + j;
    bf1r[j] = bf[3 * f + 1];
    bf2r[j] = bf[3 * f + 2];
  }

  float dH[4] = {0.f, 0.f, 0.f, 0.f};
  float dV[4][3] = {};

  for (int t = 0; t < ntiles; ++t) {
    const int abase = a0 + t * 64;
    __syncthreads();  // protect ul/dl (read by previous epilogue)
    if (tid < 64) {
      const int a = abase + tid;
      float d, ux, uy, uz;
      if (a < a_end) {
        const float dx = xyz[(size_t)(b * NA + a) * 3 + 0] - cgx;
        const float dy = xyz[(size_t)(b * NA + a) * 3 + 1] - cgy;
        const float dz = xyz[(size_t)(b * NA + a) * 3 + 2] - cgz;
        d = sqrtf(dx * dx + dy * dy + dz * dz);
        const float inv = 1.0f / d;
        ux = dx * inv; uy = dy * inv; uz = dz * inv;
      } else {
        d = 40.0f;  // g = exp(-(40-o)^2) == 0 for all offsets
        ux = uy = uz = 0.0f;
      }
      dl[tid] = d;
      ul[tid * 3 + 0] = ux; ul[tid * 3 + 1] = uy; ul[tid * 3 + 2] = uz;
    }
    __syncthreads();
    // Fill G: 8192 entries, 32 per thread.
#pragma unroll
    for (int i = 0; i < 32; ++i) {
      const int idx = tid + i * 256;
      const int k = idx >> 6;
      const int a = idx & 63;
      const float o = (float)k * (5.0f / 127.0f);
      const float dd = dl[a] - o;
      G[idx] = __expf(-dd * dd);
    }

    float acc1[8][4] = {};
    float acc2[8][4] = {};
    for (int ch = 0; ch < FDIM / KC; ++ch) {
      __syncthreads();
#pragma unroll
      for (int i = 0; i < 2; ++i) {
        const int idx = (tid + i * 256) * 4;
        *(float4*)&Wc1[idx] = *(const float4*)&Wf1T[ch * KC * FDIM + idx];
        *(float4*)&Wc2[idx] = *(const float4*)&Wf2T[ch * KC * FDIM + idx];
      }
      __syncthreads();
#pragma unroll 4
      for (int kk = 0; kk < KC; ++kk) {
        const float4 w1 = *(const float4*)&Wc1[kk * FDIM + fg * 4];
        const float4 w2 = *(const float4*)&Wc2[kk * FDIM + fg * 4];
        const int krow = (ch * KC + kk) * 64 + ag * 8;
        const float4 ga = *(const float4*)&G[krow];
        const float4 gb = *(const float4*)&G[krow + 4];
        const float gv[8] = {ga.x, ga.y, ga.z, ga.w, gb.x, gb.y, gb.z, gb.w};
#pragma unroll
        for (int i = 0; i < 8; ++i) {
          acc1[i][0] = fmaf(gv[i], w1.x, acc1[i][0]);
          acc1[i][1] = fmaf(gv[i], w1.y, acc1[i][1]);
          acc1[i][2] = fmaf(gv[i], w1.z, acc1[i][2]);
          acc1[i][3] = fmaf(gv[i], w1.w, acc1[i][3]);
          acc2[i][0] = fmaf(gv[i], w2.x, acc2[i][0]);
          acc2[i][1] = fmaf(gv[i], w2.y, acc2[i][1]);
          acc2[i][2] = fmaf(gv[i], w2.z, acc2[i][2]);
          acc2[i][3] = fmaf(gv[i], w2.w, acc2[i][3]);
        }
      }
    }
    // Epilogue for this atom tile.
#pragma unroll
    for (int i = 0; i < 8; ++i) {
      const int al = ag * 8 + i;
      const int a = abase + al;
      float4 p1 = {0.f, 0.f, 0.f, 0.f}, p2 = {0.f, 0.f, 0.f, 0.f};
      if (a < a_end) {
        p1 = *(const float4*)&phi1[(size_t)(b * NA + a) * FDIM + fg * 4];
        p2 = *(const float4*)&phi2[(size_t)(b * NA + a) * FDIM + fg * 4];
      }
      const float ux = ul[al * 3 + 0], uy = ul[al * 3 + 1], uz = ul[al * 3 + 2];
      const float pp1[4] = {p1.x, p1.y, p1.z, p1.w};
      const float pp2[4] = {p2.x, p2.y, p2.z, p2.w};
#pragma unroll
      for (int j = 0; j < 4; ++j) {
        dH[j] = fmaf(acc1[i][j] + bf1r[j], pp1[j], dH[j]);
        const float t2 = (acc2[i][j] + bf2r[j]) * pp2[j];
        dV[j][0] = fmaf(t2, ux, dV[j][0]);
        dV[j][1] = fmaf(t2, uy, dV[j][1]);
        dV[j][2] = fmaf(t2, uz, dV[j][2]);
      }
    }
  }

  // Cross-ag reduction (8 partial owners per f), 4 passes through a 4 KB buffer.
  __syncthreads();
  *(float4*)&red[ag * FDIM + fg * 4] = make_float4(dH[0], dH[1], dH[2], dH[3]);
  __syncthreads();
  if (tid < FDIM) {
    float s = 0.f;
#pragma unroll
    for (int g = 0; g < 8; ++g) s += red[g * FDIM + tid];
    pH[(size_t)(az * BNC + bc) * FDIM + tid] = s;
  }
#pragma unroll
  for (int x = 0; x < 3; ++x) {
    __syncthreads();
    *(float4*)&red[ag * FDIM + fg * 4] = make_float4(dV[0][x], dV[1][x], dV[2][x], dV[3][x]);
    __syncthreads();
    if (tid < FDIM) {
      float s = 0.f;
#pragma unroll
      for (int g = 0; g < 8; ++g) s += red[g * FDIM + tid];
      pV[((size_t)(az * BNC + bc) * FDIM + tid) * 3 + x] = s;
    }
  }
}

template <int ASPLIT>
__global__ __launch_bounds__(FDIM) void reduce_kernel(
    const float* __restrict__ H, const float* __restrict__ pH, const float* __restrict__ pV,
    float* __restrict__ out, int BNC) {
  const int bc = blockIdx.x;
  const int f = threadIdx.x;
  float s = H[(size_t)bc * FDIM + f];
#pragma unroll
  for (int az = 0; az < ASPLIT; ++az) s += pH[(size_t)(az * BNC + bc) * FDIM + f];
  out[(size_t)bc * FDIM + f] = s;
  float* outV = out + (size_t)BNC * FDIM;
#pragma unroll
  for (int x = 0; x < 3; ++x) {
    float v = 0.f;
#pragma unroll
    for (int az = 0; az < ASPLIT; ++az) v += pV[((size_t)(az * BNC + bc) * FDIM + f) * 3 + x];
    outV[((size_t)bc * FDIM + f) * 3 + x] = v;
  }
}

extern "C" void kernel_launch(void* const* d_in, const int* in_sizes, int n_in,
                              void* d_out, int out_size, void* d_ws, size_t ws_size,
                              hipStream_t stream) {
  // inputs: 0 assign(int,unused), 1 h, 2 H, 3 cg_xyz, 4 xyz, 5 cg_adj(unused),
  //         6 Wf, 7 bf, 8 W1, 9 b1, 10 W2, 11 b2
  const float* h      = (const float*)d_in[1];
  const float* Hc     = (const float*)d_in[2];
  const float* cg_xyz = (const float*)d_in[3];
  const float* xyz    = (const float*)d_in[4];
  const float* Wf     = (const float*)d_in[6];
  const float* bf     = (const float*)d_in[7];
  const float* W1     = (const float*)d_in[8];
  const float* b1     = (const float*)d_in[9];
  const float* W2     = (const float*)d_in[10];
  const float* b2     = (const float*)d_in[11];

  const int BNC = in_sizes[2] / FDIM;      // B*NC
  const int NC  = in_sizes[5] / BNC;       // cg_adj = B*NC*NC
  const int B   = BNC / NC;
  const int NA  = in_sizes[0] / B;
  constexpr int ASPLIT = 4;

  float* ws = (float*)d_ws;
  const size_t oPhi1 = 0;
  const size_t oPhi2 = oPhi1 + (size_t)B * NA * FDIM;
  const size_t oWf1  = oPhi2 + (size_t)B * NA * FDIM;
  const size_t oWf2  = oWf1 + FDIM * FDIM;
  const size_t oW21  = oWf2 + FDIM * FDIM;
  const size_t oW22  = oW21 + FDIM * FDIM;
  const size_t oPH   = oW22 + FDIM * FDIM;
  const size_t oPV   = oPH + (size_t)ASPLIT * BNC * FDIM;

  pack_w_kernel<<<FDIM, FDIM, 0, stream>>>(Wf, W2, ws + oWf1, ws + oWf2, ws + oW21, ws + oW22);
  phi_kernel<<<B * NA, FDIM, 0, stream>>>(h, W1, b1, ws + oW21, ws + oW22, b2,
                                          ws + oPhi1, ws + oPhi2);
  enc_main_kernel<ASPLIT><<<dim3(ASPLIT, NC, B), 256, 0, stream>>>(
      xyz, cg_xyz, ws + oWf1, ws + oWf2, bf, ws + oPhi1, ws + oPhi2,
      ws + oPH, ws + oPV, NA, NC, BNC);
  reduce_kernel<ASPLIT><<<BNC, FDIM, 0, stream>>>(Hc, ws + oPH, ws + oPV, (float*)d_out, BNC);
}

// Round 2
// 91.581 us; speedup vs baseline: 2.0982x; 2.0982x over previous
//
#include <hip/hip_runtime.h>
#include <cmath>

#define FDIM 128

typedef __attribute__((ext_vector_type(8))) __bf16 bf16x8;
typedef __attribute__((ext_vector_type(4))) float f32x4;

__device__ inline unsigned short f2bf(float x) {
  unsigned int u = __float_as_uint(x);
  return (unsigned short)((u + 0x7FFFu + ((u >> 16) & 1u)) >> 16);
}

// Pack the used columns (3f+1, 3f+2) of W2 into [k][f] layout (fp32, for phi).
__global__ void pack_w_kernel(const float* __restrict__ W2,
                              float* __restrict__ W21T, float* __restrict__ W22T) {
  int k = blockIdx.x;
  int f = threadIdx.x;
  W21T[k * FDIM + f] = W2[k * 3 * FDIM + 3 * f + 1];
  W22T[k * FDIM + f] = W2[k * 3 * FDIM + 3 * f + 2];
}

// Pack Wf used columns into bf16 MFMA B-fragment layout:
// [ft(16)][kt(4)][lane(64)][j(8)], element = Wf[k][3*fcol+1+s]
// with k = kt*32 + (lane>>4)*8 + j, s = ft>>3, fcol = (ft&7)*16 + (lane&15).
__global__ __launch_bounds__(64) void pack_wf_frag(const float* __restrict__ Wf,
                                                   unsigned short* __restrict__ Wfrag) {
  const int ft = blockIdx.x;   // 0..15
  const int kt = blockIdx.y;   // 0..3
  const int lane = threadIdx.x;
  const int s = ft >> 3;
  const int fcol = (ft & 7) * 16 + (lane & 15);
  unsigned short g[8];
#pragma unroll
  for (int j = 0; j < 8; ++j) {
    const int k = kt * 32 + ((lane >> 4) << 3) + j;
    g[j] = f2bf(Wf[k * 3 * FDIM + 3 * fcol + 1 + s]);
  }
  uint4 u;
  u.x = g[0] | ((unsigned int)g[1] << 16);
  u.y = g[2] | ((unsigned int)g[3] << 16);
  u.z = g[4] | ((unsigned int)g[5] << 16);
  u.w = g[6] | ((unsigned int)g[7] << 16);
  *(uint4*)&Wfrag[((size_t)(ft * 4 + kt) * 64 + lane) * 8] = u;
}

// phi = silu(h@W1+b1)@W2+b2, keeping only columns 3f+1 (phi1) and 3f+2 (phi2).
__global__ __launch_bounds__(FDIM) void phi_kernel(
    const float* __restrict__ h, const float* __restrict__ W1, const float* __restrict__ b1,
    const float* __restrict__ W21T, const float* __restrict__ W22T, const float* __restrict__ b2,
    float* __restrict__ phi1, float* __restrict__ phi2) {
  __shared__ float hrow[FDIM];
  __shared__ float trow[FDIM];
  const size_t row = blockIdx.x;
  const int f = threadIdx.x;
  hrow[f] = h[row * FDIM + f];
  __syncthreads();
  float acc = b1[f];
#pragma unroll 8
  for (int k = 0; k < FDIM; ++k) acc = fmaf(hrow[k], W1[k * FDIM + f], acc);
  trow[f] = acc / (1.0f + __expf(-acc));
  __syncthreads();
  float p1 = b2[3 * f + 1];
  float p2 = b2[3 * f + 2];
#pragma unroll 8
  for (int k = 0; k < FDIM; ++k) {
    const float t = trow[k];
    p1 = fmaf(t, W21T[k * FDIM + f], p1);
    p2 = fmaf(t, W22T[k * FDIM + f], p2);
  }
  phi1[row * FDIM + f] = p1;
  phi2[row * FDIM + f] = p2;
}

// MFMA main kernel. Grid (ASPLIT, NC, B), 256 threads = 4 waves.
// Wave w owns f'-columns [w*64, w*64+64): waves 0,1 -> split1 (dH),
// waves 2,3 -> split2 (dV). B fragments live in registers (16 per wave).
// Per 64-atom tile: G generated into A-fragment-layout LDS (bf16), then
// 64 MFMAs/wave, then fused phi/bias/unit epilogue into register partials.
template <int ASPLIT>
__global__ __launch_bounds__(256) void enc_main_kernel(
    const float* __restrict__ xyz, const float* __restrict__ cg_xyz,
    const unsigned short* __restrict__ Wfrag, const float* __restrict__ bf,
    const float* __restrict__ phi1, const float* __restrict__ phi2,
    float* __restrict__ pH, float* __restrict__ pV,
    int NA, int NC, int BNC) {
  __shared__ unsigned short Gl[4 * 4 * 64 * 8];  // 16 KB: [sub][kt][lane][8]
  __shared__ float dl[64];
  __shared__ float ul[64 * 3];

  const int az = blockIdx.x;
  const int c = blockIdx.y;
  const int b = blockIdx.z;
  const int bc = b * NC + c;
  const int tid = threadIdx.x;
  const int lane = tid & 63;
  const int w = tid >> 6;
  const int s = w >> 1;              // 0: split1/dH, 1: split2/dV
  const int hw = lane >> 4;          // 0..3 lane group
  const int lcol = lane & 15;

  const float cgx = cg_xyz[bc * 3 + 0];
  const float cgy = cg_xyz[bc * 3 + 1];
  const float cgz = cg_xyz[bc * 3 + 2];

  const int APA = (NA + ASPLIT - 1) / ASPLIT;
  const int a0 = az * APA;
  const int a_end = min(NA, a0 + APA);
  const int ntiles = (APA + 63) >> 6;

  // B fragments (registers, persistent): ft = w*4 + ftl.
  bf16x8 Bf[4][4];
#pragma unroll
  for (int ftl = 0; ftl < 4; ++ftl)
#pragma unroll
    for (int kt = 0; kt < 4; ++kt)
      Bf[ftl][kt] = *reinterpret_cast<const bf16x8*>(
          &Wfrag[(((size_t)(w * 4 + ftl) * 4 + kt) * 64 + lane) * 8]);

  // Per-lane f columns and biases.
  int fcols[4];
  float bfv[4];
#pragma unroll
  for (int ftl = 0; ftl < 4; ++ftl) {
    fcols[ftl] = (w & 1) * 64 + ftl * 16 + lcol;
    bfv[ftl] = bf[3 * fcols[ftl] + 1 + s];
  }

  float dHp[4] = {0.f, 0.f, 0.f, 0.f};
  float dVp[4][3] = {};

  const float* __restrict__ phis = s ? phi2 : phi1;

  for (int t = 0; t < ntiles; ++t) {
    const int abase = a0 + t * 64;
    __syncthreads();  // protect ul/dl against previous epilogue readers
    if (tid < 64) {
      const int a = abase + tid;
      float d, ux, uy, uz;
      if (a < a_end) {
        const float dx = xyz[(size_t)(b * NA + a) * 3 + 0] - cgx;
        const float dy = xyz[(size_t)(b * NA + a) * 3 + 1] - cgy;
        const float dz = xyz[(size_t)(b * NA + a) * 3 + 2] - cgz;
        d = sqrtf(dx * dx + dy * dy + dz * dz);
        const float inv = 1.0f / d;
        ux = dx * inv; uy = dy * inv; uz = dz * inv;
      } else {
        d = 40.0f;  // exp(-(40-o)^2) == 0 for all offsets
        ux = uy = uz = 0.0f;
      }
      dl[tid] = d;
      ul[tid * 3 + 0] = ux; ul[tid * 3 + 1] = uy; ul[tid * 3 + 2] = uz;
    }
    __syncthreads();
    // G generation straight into A-fragment layout (row=lane&15 -> atom,
    // k=(lane>>4)*8+j). 32 expf/thread.
#pragma unroll
    for (int i = 0; i < 4; ++i) {
      const int idx = i * 256 + tid;
      const int gl = idx & 63;
      const int kt = (idx >> 6) & 3;
      const int sub = idx >> 8;
      const float d = dl[sub * 16 + (gl & 15)];
      const int kb = kt * 32 + ((gl >> 4) << 3);
      unsigned short g[8];
#pragma unroll
      for (int j = 0; j < 8; ++j) {
        const float dd = d - (float)(kb + j) * (5.0f / 127.0f);
        g[j] = f2bf(__expf(-dd * dd));
      }
      uint4 u;
      u.x = g[0] | ((unsigned int)g[1] << 16);
      u.y = g[2] | ((unsigned int)g[3] << 16);
      u.z = g[4] | ((unsigned int)g[5] << 16);
      u.w = g[6] | ((unsigned int)g[7] << 16);
      *(uint4*)&Gl[idx * 8] = u;
    }
    __syncthreads();

    // MFMA: S[64 atoms][64 f'] per wave.
    f32x4 acc[4][4];
#pragma unroll
    for (int sub = 0; sub < 4; ++sub)
#pragma unroll
      for (int ftl = 0; ftl < 4; ++ftl)
        acc[sub][ftl] = (f32x4){0.f, 0.f, 0.f, 0.f};

#pragma unroll
    for (int sub = 0; sub < 4; ++sub) {
      bf16x8 ga[4];
#pragma unroll
      for (int kt = 0; kt < 4; ++kt)
        ga[kt] = *reinterpret_cast<const bf16x8*>(
            &Gl[((sub * 4 + kt) * 64 + lane) * 8]);
#pragma unroll
      for (int ftl = 0; ftl < 4; ++ftl)
#pragma unroll
        for (int kt = 0; kt < 4; ++kt)
          acc[sub][ftl] = __builtin_amdgcn_mfma_f32_16x16x32_bf16(
              ga[kt], Bf[ftl][kt], acc[sub][ftl], 0, 0, 0);
    }

    // Fused epilogue. C layout: col=lane&15 (f), row=(lane>>4)*4+reg (atom).
#pragma unroll
    for (int sub = 0; sub < 4; ++sub) {
#pragma unroll
      for (int reg = 0; reg < 4; ++reg) {
        const int a_loc = sub * 16 + hw * 4 + reg;
        const int a = abase + a_loc;
        const bool ok = (a < a_end);
        const size_t prow = (size_t)(b * NA + a) * FDIM;
        const float u0 = ul[a_loc * 3 + 0];
        const float u1 = ul[a_loc * 3 + 1];
        const float u2 = ul[a_loc * 3 + 2];
#pragma unroll
        for (int ftl = 0; ftl < 4; ++ftl) {
          const float p = ok ? phis[prow + fcols[ftl]] : 0.f;
          const float sv = acc[sub][ftl][reg] + bfv[ftl];
          if (s == 0) {
            dHp[ftl] = fmaf(sv, p, dHp[ftl]);
          } else {
            const float t2 = sv * p;
            dVp[ftl][0] = fmaf(t2, u0, dVp[ftl][0]);
            dVp[ftl][1] = fmaf(t2, u1, dVp[ftl][1]);
            dVp[ftl][2] = fmaf(t2, u2, dVp[ftl][2]);
          }
        }
      }
    }
  }

  // Lane-group reduction: lanes l, l+16, l+32, l+48 share the same f column.
#pragma unroll
  for (int ftl = 0; ftl < 4; ++ftl) {
    if (s == 0) {
      float v = dHp[ftl];
      v += __shfl_xor(v, 16);
      v += __shfl_xor(v, 32);
      if (lane < 16)
        pH[(size_t)(az * BNC + bc) * FDIM + fcols[ftl]] = v;
    } else {
#pragma unroll
      for (int x = 0; x < 3; ++x) {
        float v = dVp[ftl][x];
        v += __shfl_xor(v, 16);
        v += __shfl_xor(v, 32);
        if (lane < 16)
          pV[((size_t)(az * BNC + bc) * FDIM + fcols[ftl]) * 3 + x] = v;
      }
    }
  }
}

template <int ASPLIT>
__global__ __launch_bounds__(FDIM) void reduce_kernel(
    const float* __restrict__ H, const float* __restrict__ pH, const float* __restrict__ pV,
    float* __restrict__ out, int BNC) {
  const int bc = blockIdx.x;
  const int f = threadIdx.x;
  float s = H[(size_t)bc * FDIM + f];
#pragma unroll
  for (int az = 0; az < ASPLIT; ++az) s += pH[(size_t)(az * BNC + bc) * FDIM + f];
  out[(size_t)bc * FDIM + f] = s;
  float* outV = out + (size_t)BNC * FDIM;
#pragma unroll
  for (int x = 0; x < 3; ++x) {
    float v = 0.f;
#pragma unroll
    for (int az = 0; az < ASPLIT; ++az) v += pV[((size_t)(az * BNC + bc) * FDIM + f) * 3 + x];
    outV[((size_t)bc * FDIM + f) * 3 + x] = v;
  }
}

extern "C" void kernel_launch(void* const* d_in, const int* in_sizes, int n_in,
                              void* d_out, int out_size, void* d_ws, size_t ws_size,
                              hipStream_t stream) {
  // inputs: 0 assign(unused), 1 h, 2 H, 3 cg_xyz, 4 xyz, 5 cg_adj(unused),
  //         6 Wf, 7 bf, 8 W1, 9 b1, 10 W2, 11 b2
  const float* h      = (const float*)d_in[1];
  const float* Hc     = (const float*)d_in[2];
  const float* cg_xyz = (const float*)d_in[3];
  const float* xyz    = (const float*)d_in[4];
  const float* Wf     = (const float*)d_in[6];
  const float* bf     = (const float*)d_in[7];
  const float* W1     = (const float*)d_in[8];
  const float* b1     = (const float*)d_in[9];
  const float* W2     = (const float*)d_in[10];
  const float* b2     = (const float*)d_in[11];

  const int BNC = in_sizes[2] / FDIM;      // B*NC
  const int NC  = in_sizes[5] / BNC;       // cg_adj = B*NC*NC
  const int B   = BNC / NC;
  const int NA  = in_sizes[0] / B;
  constexpr int ASPLIT = 8;

  float* ws = (float*)d_ws;
  const size_t oPhi1 = 0;
  const size_t oPhi2 = oPhi1 + (size_t)B * NA * FDIM;
  const size_t oW21  = oPhi2 + (size_t)B * NA * FDIM;
  const size_t oW22  = oW21 + FDIM * FDIM;
  const size_t oWfr  = oW22 + FDIM * FDIM;            // 16*4*64*8 ushorts = 16384 floats
  const size_t oPH   = oWfr + 16 * 4 * 64 * 8 / 2;
  const size_t oPV   = oPH + (size_t)ASPLIT * BNC * FDIM;

  pack_w_kernel<<<FDIM, FDIM, 0, stream>>>(W2, ws + oW21, ws + oW22);
  pack_wf_frag<<<dim3(16, 4), 64, 0, stream>>>(Wf, (unsigned short*)(ws + oWfr));
  phi_kernel<<<B * NA, FDIM, 0, stream>>>(h, W1, b1, ws + oW21, ws + oW22, b2,
                                          ws + oPhi1, ws + oPhi2);
  enc_main_kernel<ASPLIT><<<dim3(ASPLIT, NC, B), 256, 0, stream>>>(
      xyz, cg_xyz, (const unsigned short*)(ws + oWfr), bf,
      ws + oPhi1, ws + oPhi2, ws + oPH, ws + oPV, NA, NC, BNC);
  reduce_kernel<ASPLIT><<<BNC, FDIM, 0, stream>>>(Hc, ws + oPH, ws + oPV, (float*)d_out, BNC);
}

// Round 4
// 45.384 us; speedup vs baseline: 4.2340x; 2.0179x over previous
//
#include <hip/hip_runtime.h>
#include <cmath>

#define FDIM 128

typedef __attribute__((ext_vector_type(8))) __bf16 bf16x8;
typedef __attribute__((ext_vector_type(4))) float f32x4;

// RNE f32 -> bf16 bits (cold paths)
__device__ inline unsigned short f2bf(float x) {
  unsigned int u = __float_as_uint(x);
  return (unsigned short)((u + 0x7FFFu + ((u >> 16) & 1u)) >> 16);
}
__device__ inline float bfw_lo(unsigned int w) { return __uint_as_float(w << 16); }
__device__ inline float bfw_hi(unsigned int w) { return __uint_as_float(w & 0xFFFF0000u); }

// Pack weights into bf16 MFMA B-fragment layout [ft][kt][lane][j].
// mode 0: W is [128][128], col = ft*16 + (lane&15).
// mode 1: W is [128][384], col = 3*((ft&7)*16 + (lane&15)) + 1 + (ft>>3).
__global__ __launch_bounds__(64) void pack_frag_kernel(const float* __restrict__ W,
                                                       unsigned short* __restrict__ out,
                                                       int mode) {
  const int ft = blockIdx.x, kt = blockIdx.y;
  const int lane = threadIdx.x;
  int col, stride;
  if (mode == 0) { col = ft * 16 + (lane & 15); stride = 128; }
  else { col = 3 * ((ft & 7) * 16 + (lane & 15)) + 1 + (ft >> 3); stride = 384; }
  unsigned short g[8];
#pragma unroll
  for (int j = 0; j < 8; ++j) {
    const int k = kt * 32 + ((lane >> 4) << 3) + j;
    g[j] = f2bf(W[(size_t)k * stride + col]);
  }
  uint4 u;
  u.x = g[0] | ((unsigned int)g[1] << 16);
  u.y = g[2] | ((unsigned int)g[3] << 16);
  u.z = g[4] | ((unsigned int)g[5] << 16);
  u.w = g[6] | ((unsigned int)g[7] << 16);
  *(uint4*)&out[((size_t)(ft * 4 + kt) * 64 + lane) * 8] = u;
}

// phi = silu(h@W1+b1)@W2+b2 (used cols only), via two MFMA passes.
// 32 rows per block, 4 waves. Output: phiP[s][row][q] u32 packing
// (phi[fblock*32+lcol], phi[fblock*32+16+lcol]) with q = fblock*16+lcol.
__global__ __launch_bounds__(256) void phi_mfma_kernel(
    const float* __restrict__ h, const float* __restrict__ b1, const float* __restrict__ b2,
    const unsigned short* __restrict__ W1f, const unsigned short* __restrict__ W2f,
    unsigned int* __restrict__ phiP, int BNA) {
  __shared__ __bf16 hA[2 * 4 * 64 * 8];       // 8 KB: h tile, A-frag layout
  __shared__ unsigned short tS[32 * 128];     // 8 KB: t tile, swizzled row-major
  const int tid = threadIdx.x;
  const int lane = tid & 63;
  const int w = tid >> 6;       // 0..3
  const int hw = lane >> 4, lcol = lane & 15;
  const int r0 = blockIdx.x * 32;

  // stage h -> A-frag bf16
#pragma unroll
  for (int i = 0; i < 2; ++i) {
    const int idx = i * 256 + tid;
    const int gl = idx & 63;
    const int kt = (idx >> 6) & 3;
    const int sub = idx >> 8;
    const int row = sub * 16 + (gl & 15);
    const int k0 = kt * 32 + ((gl >> 4) << 3);
    const int gr = r0 + row;
    bf16x8 v;
    if (gr < BNA) {
      const float4 f0 = *(const float4*)&h[(size_t)gr * FDIM + k0];
      const float4 f1 = *(const float4*)&h[(size_t)gr * FDIM + k0 + 4];
      v[0] = (__bf16)f0.x; v[1] = (__bf16)f0.y; v[2] = (__bf16)f0.z; v[3] = (__bf16)f0.w;
      v[4] = (__bf16)f1.x; v[5] = (__bf16)f1.y; v[6] = (__bf16)f1.z; v[7] = (__bf16)f1.w;
    } else {
#pragma unroll
      for (int j = 0; j < 8; ++j) v[j] = (__bf16)0.0f;
    }
    *reinterpret_cast<bf16x8*>(&hA[idx * 8]) = v;
  }

  // pass1 B-frags (W1): wave w -> f-cols [w*32, w*32+32)
  bf16x8 B1[2][4];
#pragma unroll
  for (int ftl = 0; ftl < 2; ++ftl)
#pragma unroll
    for (int kt = 0; kt < 4; ++kt)
      B1[ftl][kt] = *reinterpret_cast<const bf16x8*>(
          &W1f[(((size_t)(w * 2 + ftl) * 4 + kt) * 64 + lane) * 8]);
  float b1v[2];
#pragma unroll
  for (int ftl = 0; ftl < 2; ++ftl) b1v[ftl] = b1[w * 32 + ftl * 16 + lcol];
  __syncthreads();

#pragma unroll
  for (int sub = 0; sub < 2; ++sub) {
    bf16x8 ga[4];
#pragma unroll
    for (int kt = 0; kt < 4; ++kt)
      ga[kt] = *reinterpret_cast<const bf16x8*>(&hA[((sub * 4 + kt) * 64 + lane) * 8]);
    f32x4 acc[2];
    acc[0] = (f32x4){0.f, 0.f, 0.f, 0.f};
    acc[1] = (f32x4){0.f, 0.f, 0.f, 0.f};
#pragma unroll
    for (int ftl = 0; ftl < 2; ++ftl)
#pragma unroll
      for (int kt = 0; kt < 4; ++kt)
        acc[ftl] = __builtin_amdgcn_mfma_f32_16x16x32_bf16(ga[kt], B1[ftl][kt], acc[ftl], 0, 0, 0);
#pragma unroll
    for (int ftl = 0; ftl < 2; ++ftl)
#pragma unroll
      for (int reg = 0; reg < 4; ++reg) {
        const int row = sub * 16 + hw * 4 + reg;
        const int fcol = w * 32 + ftl * 16 + lcol;
        const float x = acc[ftl][reg] + b1v[ftl];
        const float t = x / (1.0f + __expf(-x));
        const int byte = (row * 256 + fcol * 2) ^ ((row & 7) << 4);
        *(unsigned short*)((char*)tS + byte) = f2bf(t);
      }
  }

  // pass2 B-frags (W2 used cols): wave w -> 64 of 256 f'-cols
  bf16x8 B2[4][4];
#pragma unroll
  for (int ftl = 0; ftl < 4; ++ftl)
#pragma unroll
    for (int kt = 0; kt < 4; ++kt)
      B2[ftl][kt] = *reinterpret_cast<const bf16x8*>(
          &W2f[(((size_t)(w * 4 + ftl) * 4 + kt) * 64 + lane) * 8]);
  const int s = w >> 1;
  float blo[2], bhi[2];
#pragma unroll
  for (int p = 0; p < 2; ++p) {
    const int f_lo = (w & 1) * 64 + p * 32 + lcol;
    blo[p] = b2[3 * f_lo + 1 + s];
    bhi[p] = b2[3 * (f_lo + 16) + 1 + s];
  }
  __syncthreads();

#pragma unroll
  for (int sub = 0; sub < 2; ++sub) {
    bf16x8 ta[4];
#pragma unroll
    for (int kt = 0; kt < 4; ++kt) {
      const int row = sub * 16 + lcol;
      const int k0 = kt * 32 + hw * 8;
      const int byte = (row * 256 + k0 * 2) ^ ((row & 7) << 4);
      ta[kt] = *reinterpret_cast<const bf16x8*>((const char*)tS + byte);
    }
    f32x4 acc[4];
#pragma unroll
    for (int ftl = 0; ftl < 4; ++ftl) acc[ftl] = (f32x4){0.f, 0.f, 0.f, 0.f};
#pragma unroll
    for (int ftl = 0; ftl < 4; ++ftl)
#pragma unroll
      for (int kt = 0; kt < 4; ++kt)
        acc[ftl] = __builtin_amdgcn_mfma_f32_16x16x32_bf16(ta[kt], B2[ftl][kt], acc[ftl], 0, 0, 0);
#pragma unroll
    for (int p = 0; p < 2; ++p)
#pragma unroll
      for (int reg = 0; reg < 4; ++reg) {
        const int row = sub * 16 + hw * 4 + reg;
        const int gr = r0 + row;
        if (gr < BNA) {
          const float vlo = acc[2 * p][reg] + blo[p];
          const float vhi = acc[2 * p + 1][reg] + bhi[p];
          const unsigned int word = f2bf(vlo) | ((unsigned int)f2bf(vhi) << 16);
          phiP[(size_t)s * BNA * 64 + (size_t)gr * 64 + ((w & 1) * 2 + p) * 16 + lcol] = word;
        }
      }
  }
}

// Main fused kernel: 512 threads = 8 waves. Wave w: split s=w>>2, f-block
// fb=w&3 (32 f-cols). Per 64-atom tile: G into A-frag LDS via exp-recurrence,
// 32 MFMAs/wave, fused phi/bias/unit epilogue with prefetched packed-phi.
template <int ASPLIT>
__global__ __launch_bounds__(512, 4) void enc_main_kernel(
    const float* __restrict__ xyz, const float* __restrict__ cg_xyz,
    const unsigned short* __restrict__ Wff, const float* __restrict__ bf,
    const unsigned int* __restrict__ phiP,
    float* __restrict__ pH, float* __restrict__ pV,
    int NA, int NC, int BNC, int BNA) {
  __shared__ __bf16 Gl[4 * 4 * 64 * 8];  // 16 KB A-frag layout
  __shared__ float dl[64];
  __shared__ float ul[64 * 3];

  const int az = blockIdx.x;
  const int c = blockIdx.y;
  const int b = blockIdx.z;
  const int bc = b * NC + c;
  const int tid = threadIdx.x;
  const int lane = tid & 63;
  const int w = tid >> 6;        // 0..7
  const int s = w >> 2;          // 0: dH, 1: dV
  const int fb = w & 3;          // 32-col f-block
  const int hw = lane >> 4, lcol = lane & 15;

  const float cgx = cg_xyz[bc * 3 + 0];
  const float cgy = cg_xyz[bc * 3 + 1];
  const float cgz = cg_xyz[bc * 3 + 2];

  const int APA = (NA + ASPLIT - 1) / ASPLIT;
  const int a0 = az * APA;
  const int a_end = min(NA, a0 + APA);
  const int ntiles = (APA + 63) >> 6;

  // B fragments: ft = s*8 + fb*2 + ftl  (32 VGPR)
  bf16x8 Bf[2][4];
#pragma unroll
  for (int ftl = 0; ftl < 2; ++ftl)
#pragma unroll
    for (int kt = 0; kt < 4; ++kt)
      Bf[ftl][kt] = *reinterpret_cast<const bf16x8*>(
          &Wff[(((size_t)(s * 8 + fb * 2 + ftl) * 4 + kt) * 64 + lane) * 8]);

  float bfv[2];
#pragma unroll
  for (int ftl = 0; ftl < 2; ++ftl)
    bfv[ftl] = bf[3 * (fb * 32 + ftl * 16 + lcol) + 1 + s];

  const unsigned int* __restrict__ phiS = phiP + (size_t)s * BNA * 64;

  float dHp[2] = {0.f, 0.f};
  float dVp[2][3] = {};

  constexpr float DLT = 5.0f / 127.0f;
  constexpr float DLT2 = DLT * DLT;
  constexpr float E2C = 0.99690479f;  // exp(-2*DLT^2)

  for (int t = 0; t < ntiles; ++t) {
    const int abase = a0 + t * 64;
    __syncthreads();  // prev-tile epilogue done reading ul; Gl reads done
    if (tid < 64) {
      const int a = abase + tid;
      float d, ux, uy, uz;
      if (a < a_end) {
        const float dx = xyz[(size_t)(b * NA + a) * 3 + 0] - cgx;
        const float dy = xyz[(size_t)(b * NA + a) * 3 + 1] - cgy;
        const float dz = xyz[(size_t)(b * NA + a) * 3 + 2] - cgz;
        d = sqrtf(dx * dx + dy * dy + dz * dz);
        const float inv = 1.0f / d;
        ux = dx * inv; uy = dy * inv; uz = dz * inv;
      } else {
        d = 40.0f;  // exp(-(40-o)^2) == 0 for all offsets
        ux = uy = uz = 0.0f;
      }
      dl[tid] = d;
      ul[tid * 3 + 0] = ux; ul[tid * 3 + 1] = uy; ul[tid * 3 + 2] = uz;
    }

    // phi prefetch: one packed u32 per (sub,reg); hides L2 latency under MFMA
    unsigned int pf[4][4];
#pragma unroll
    for (int sub = 0; sub < 4; ++sub)
#pragma unroll
      for (int reg = 0; reg < 4; ++reg) {
        const int a = abase + sub * 16 + hw * 4 + reg;
        pf[sub][reg] = (a < a_end)
            ? phiS[(size_t)(b * NA + a) * 64 + fb * 16 + lcol] : 0u;
      }
    __syncthreads();

    // G generation: exp recurrence, 2 groups of 8 per thread
#pragma unroll
    for (int i = 0; i < 2; ++i) {
      const int idx = i * 512 + tid;
      const int gl = idx & 63;
      const int kt = (idx >> 6) & 3;
      const int sub = idx >> 8;
      const int kb = kt * 32 + ((gl >> 4) << 3);
      const float d = dl[sub * 16 + (gl & 15)];
      const float d0 = d - (float)kb * DLT;
      float g = __expf(-d0 * d0);
      float mult = __expf(2.0f * DLT * d - (float)(2 * kb + 1) * DLT2);
      bf16x8 gv;
#pragma unroll
      for (int j = 0; j < 8; ++j) {
        gv[j] = (__bf16)g;
        g *= mult;
        mult *= E2C;
      }
      *reinterpret_cast<bf16x8*>(&Gl[idx * 8]) = gv;
    }
    __syncthreads();

    // MFMA + fused epilogue, per 16-atom sub-tile
#pragma unroll
    for (int sub = 0; sub < 4; ++sub) {
      bf16x8 ga[4];
#pragma unroll
      for (int kt = 0; kt < 4; ++kt)
        ga[kt] = *reinterpret_cast<const bf16x8*>(&Gl[((sub * 4 + kt) * 64 + lane) * 8]);
      f32x4 acc[2];
      acc[0] = (f32x4){0.f, 0.f, 0.f, 0.f};
      acc[1] = (f32x4){0.f, 0.f, 0.f, 0.f};
#pragma unroll
      for (int ftl = 0; ftl < 2; ++ftl)
#pragma unroll
        for (int kt = 0; kt < 4; ++kt)
          acc[ftl] = __builtin_amdgcn_mfma_f32_16x16x32_bf16(ga[kt], Bf[ftl][kt], acc[ftl], 0, 0, 0);
#pragma unroll
      for (int reg = 0; reg < 4; ++reg) {
        const int a_loc = sub * 16 + hw * 4 + reg;
        const unsigned int pw = pf[sub][reg];
        const float plo = bfw_lo(pw);
        const float phi_ = bfw_hi(pw);
        if (s == 0) {
          dHp[0] = fmaf(acc[0][reg] + bfv[0], plo, dHp[0]);
          dHp[1] = fmaf(acc[1][reg] + bfv[1], phi_, dHp[1]);
        } else {
          const float u0 = ul[a_loc * 3 + 0];
          const float u1 = ul[a_loc * 3 + 1];
          const float u2 = ul[a_loc * 3 + 2];
          const float t0 = (acc[0][reg] + bfv[0]) * plo;
          const float t1 = (acc[1][reg] + bfv[1]) * phi_;
          dVp[0][0] = fmaf(t0, u0, dVp[0][0]);
          dVp[0][1] = fmaf(t0, u1, dVp[0][1]);
          dVp[0][2] = fmaf(t0, u2, dVp[0][2]);
          dVp[1][0] = fmaf(t1, u0, dVp[1][0]);
          dVp[1][1] = fmaf(t1, u1, dVp[1][1]);
          dVp[1][2] = fmaf(t1, u2, dVp[1][2]);
        }
      }
    }
  }

  // reduce across hw groups (lanes sharing lcol) and store partials
#pragma unroll
  for (int ftl = 0; ftl < 2; ++ftl) {
    const int f = fb * 32 + ftl * 16 + lcol;
    if (s == 0) {
      float v = dHp[ftl];
      v += __shfl_xor(v, 16);
      v += __shfl_xor(v, 32);
      if (lane < 16)
        pH[(size_t)(az * BNC + bc) * FDIM + f] = v;
    } else {
#pragma unroll
      for (int x = 0; x < 3; ++x) {
        float v = dVp[ftl][x];
        v += __shfl_xor(v, 16);
        v += __shfl_xor(v, 32);
        if (lane < 16)
          pV[((size_t)(az * BNC + bc) * FDIM + f) * 3 + x] = v;
      }
    }
  }
}

template <int ASPLIT>
__global__ __launch_bounds__(FDIM) void reduce_kernel(
    const float* __restrict__ H, const float* __restrict__ pH, const float* __restrict__ pV,
    float* __restrict__ out, int BNC) {
  const int bc = blockIdx.x;
  const int f = threadIdx.x;
  float s = H[(size_t)bc * FDIM + f];
#pragma unroll
  for (int az = 0; az < ASPLIT; ++az) s += pH[(size_t)(az * BNC + bc) * FDIM + f];
  out[(size_t)bc * FDIM + f] = s;
  float* outV = out + (size_t)BNC * FDIM;
#pragma unroll
  for (int x = 0; x < 3; ++x) {
    float v = 0.f;
#pragma unroll
    for (int az = 0; az < ASPLIT; ++az) v += pV[((size_t)(az * BNC + bc) * FDIM + f) * 3 + x];
    outV[((size_t)bc * FDIM + f) * 3 + x] = v;
  }
}

extern "C" void kernel_launch(void* const* d_in, const int* in_sizes, int n_in,
                              void* d_out, int out_size, void* d_ws, size_t ws_size,
                              hipStream_t stream) {
  // inputs: 0 assign(unused), 1 h, 2 H, 3 cg_xyz, 4 xyz, 5 cg_adj(unused),
  //         6 Wf, 7 bf, 8 W1, 9 b1, 10 W2, 11 b2
  const float* h      = (const float*)d_in[1];
  const float* Hc     = (const float*)d_in[2];
  const float* cg_xyz = (const float*)d_in[3];
  const float* xyz    = (const float*)d_in[4];
  const float* Wf     = (const float*)d_in[6];
  const float* bf     = (const float*)d_in[7];
  const float* W1     = (const float*)d_in[8];
  const float* b1     = (const float*)d_in[9];
  const float* W2     = (const float*)d_in[10];
  const float* b2     = (const float*)d_in[11];

  const int BNC = in_sizes[2] / FDIM;      // B*NC
  const int NC  = in_sizes[5] / BNC;       // cg_adj = B*NC*NC
  const int B   = BNC / NC;
  const int NA  = in_sizes[0] / B;
  const int BNA = B * NA;
  constexpr int ASPLIT = 4;

  // Workspace layout (BYTES — W1f is 8*4*64*8 ushorts = 32768 B, was the R3 bug):
  char* wsb = (char*)d_ws;
  unsigned short* W1f = (unsigned short*)wsb;                        // 32768 B
  unsigned short* Wff = (unsigned short*)(wsb + 32768);              // 65536 B
  unsigned short* W2f = (unsigned short*)(wsb + 32768 + 65536);      // 65536 B
  unsigned int*  phiP = (unsigned int*)(wsb + 32768 + 2 * 65536);    // 2*BNA*64*4 B
  float* pH = (float*)(wsb + 32768 + 2 * 65536 + (size_t)2 * BNA * 64 * 4);
  float* pV = pH + (size_t)ASPLIT * BNC * FDIM;

  pack_frag_kernel<<<dim3(8, 4), 64, 0, stream>>>(W1, W1f, 0);
  pack_frag_kernel<<<dim3(16, 4), 64, 0, stream>>>(Wf, Wff, 1);
  pack_frag_kernel<<<dim3(16, 4), 64, 0, stream>>>(W2, W2f, 1);
  phi_mfma_kernel<<<(BNA + 31) / 32, 256, 0, stream>>>(h, b1, b2, W1f, W2f, phiP, BNA);
  enc_main_kernel<ASPLIT><<<dim3(ASPLIT, NC, B), 512, 0, stream>>>(
      xyz, cg_xyz, Wff, bf, phiP, pH, pV, NA, NC, BNC, BNA);
  reduce_kernel<ASPLIT><<<BNC, FDIM, 0, stream>>>(Hc, pH, pV, (float*)d_out, BNC);
}

// Round 5
// 41.229 us; speedup vs baseline: 4.6607x; 1.1008x over previous
//
#include <hip/hip_runtime.h>
#include <cmath>

#define FDIM 128

typedef __attribute__((ext_vector_type(8))) __bf16 bf16x8;
typedef __attribute__((ext_vector_type(4))) float f32x4;

// RNE f32 -> bf16 bits (cold paths)
__device__ inline unsigned short f2bf(float x) {
  unsigned int u = __float_as_uint(x);
  return (unsigned short)((u + 0x7FFFu + ((u >> 16) & 1u)) >> 16);
}
__device__ inline float bfw_lo(unsigned int w) { return __uint_as_float(w << 16); }
__device__ inline float bfw_hi(unsigned int w) { return __uint_as_float(w & 0xFFFF0000u); }

// Pack all three weight mats into bf16 MFMA B-fragment layout [ft][kt][lane][j].
// z=0: W1 [128][128] (8 ft), z=1: Wf [128][384] used cols, z=2: W2 [128][384] used cols.
__global__ __launch_bounds__(64) void pack_frag_kernel(
    const float* __restrict__ W1, const float* __restrict__ Wf, const float* __restrict__ W2,
    unsigned short* __restrict__ W1f, unsigned short* __restrict__ Wff,
    unsigned short* __restrict__ W2f) {
  const int ft = blockIdx.x, kt = blockIdx.y, z = blockIdx.z;
  const int lane = threadIdx.x;
  const float* W;
  unsigned short* out;
  int col, stride;
  if (z == 0) {
    if (ft >= 8) return;
    W = W1; out = W1f; col = ft * 16 + (lane & 15); stride = 128;
  } else {
    W = (z == 1) ? Wf : W2;
    out = (z == 1) ? Wff : W2f;
    col = 3 * ((ft & 7) * 16 + (lane & 15)) + 1 + (ft >> 3);
    stride = 384;
  }
  unsigned short g[8];
#pragma unroll
  for (int j = 0; j < 8; ++j) {
    const int k = kt * 32 + ((lane >> 4) << 3) + j;
    g[j] = f2bf(W[(size_t)k * stride + col]);
  }
  uint4 u;
  u.x = g[0] | ((unsigned int)g[1] << 16);
  u.y = g[2] | ((unsigned int)g[3] << 16);
  u.z = g[4] | ((unsigned int)g[5] << 16);
  u.w = g[6] | ((unsigned int)g[7] << 16);
  *(uint4*)&out[((size_t)(ft * 4 + kt) * 64 + lane) * 8] = u;
}

// phi = silu(h@W1+b1)@W2+b2 (used cols only), via two MFMA passes.
// 32 rows per block, 4 waves. Output: phiP[s][row][q] u32 packing
// (phi[fblock*32+lcol], phi[fblock*32+16+lcol]) with q = fblock*16+lcol.
__global__ __launch_bounds__(256) void phi_mfma_kernel(
    const float* __restrict__ h, const float* __restrict__ b1, const float* __restrict__ b2,
    const unsigned short* __restrict__ W1f, const unsigned short* __restrict__ W2f,
    unsigned int* __restrict__ phiP, int BNA) {
  __shared__ __bf16 hA[2 * 4 * 64 * 8];       // 8 KB: h tile, A-frag layout
  __shared__ unsigned short tS[32 * 128];     // 8 KB: t tile, swizzled row-major
  const int tid = threadIdx.x;
  const int lane = tid & 63;
  const int w = tid >> 6;       // 0..3
  const int hw = lane >> 4, lcol = lane & 15;
  const int r0 = blockIdx.x * 32;

  // stage h -> A-frag bf16
#pragma unroll
  for (int i = 0; i < 2; ++i) {
    const int idx = i * 256 + tid;
    const int gl = idx & 63;
    const int kt = (idx >> 6) & 3;
    const int sub = idx >> 8;
    const int row = sub * 16 + (gl & 15);
    const int k0 = kt * 32 + ((gl >> 4) << 3);
    const int gr = r0 + row;
    bf16x8 v;
    if (gr < BNA) {
      const float4 f0 = *(const float4*)&h[(size_t)gr * FDIM + k0];
      const float4 f1 = *(const float4*)&h[(size_t)gr * FDIM + k0 + 4];
      v[0] = (__bf16)f0.x; v[1] = (__bf16)f0.y; v[2] = (__bf16)f0.z; v[3] = (__bf16)f0.w;
      v[4] = (__bf16)f1.x; v[5] = (__bf16)f1.y; v[6] = (__bf16)f1.z; v[7] = (__bf16)f1.w;
    } else {
#pragma unroll
      for (int j = 0; j < 8; ++j) v[j] = (__bf16)0.0f;
    }
    *reinterpret_cast<bf16x8*>(&hA[idx * 8]) = v;
  }

  // pass1 B-frags (W1): wave w -> f-cols [w*32, w*32+32)
  bf16x8 B1[2][4];
#pragma unroll
  for (int ftl = 0; ftl < 2; ++ftl)
#pragma unroll
    for (int kt = 0; kt < 4; ++kt)
      B1[ftl][kt] = *reinterpret_cast<const bf16x8*>(
          &W1f[(((size_t)(w * 2 + ftl) * 4 + kt) * 64 + lane) * 8]);
  float b1v[2];
#pragma unroll
  for (int ftl = 0; ftl < 2; ++ftl) b1v[ftl] = b1[w * 32 + ftl * 16 + lcol];
  __syncthreads();

#pragma unroll
  for (int sub = 0; sub < 2; ++sub) {
    bf16x8 ga[4];
#pragma unroll
    for (int kt = 0; kt < 4; ++kt)
      ga[kt] = *reinterpret_cast<const bf16x8*>(&hA[((sub * 4 + kt) * 64 + lane) * 8]);
    f32x4 acc[2];
    acc[0] = (f32x4){0.f, 0.f, 0.f, 0.f};
    acc[1] = (f32x4){0.f, 0.f, 0.f, 0.f};
#pragma unroll
    for (int ftl = 0; ftl < 2; ++ftl)
#pragma unroll
      for (int kt = 0; kt < 4; ++kt)
        acc[ftl] = __builtin_amdgcn_mfma_f32_16x16x32_bf16(ga[kt], B1[ftl][kt], acc[ftl], 0, 0, 0);
#pragma unroll
    for (int ftl = 0; ftl < 2; ++ftl)
#pragma unroll
      for (int reg = 0; reg < 4; ++reg) {
        const int row = sub * 16 + hw * 4 + reg;
        const int fcol = w * 32 + ftl * 16 + lcol;
        const float x = acc[ftl][reg] + b1v[ftl];
        const float t = x / (1.0f + __expf(-x));
        const int byte = (row * 256 + fcol * 2) ^ ((row & 7) << 4);
        *(unsigned short*)((char*)tS + byte) = f2bf(t);
      }
  }

  // pass2 B-frags (W2 used cols): wave w -> 64 of 256 f'-cols
  bf16x8 B2[4][4];
#pragma unroll
  for (int ftl = 0; ftl < 4; ++ftl)
#pragma unroll
    for (int kt = 0; kt < 4; ++kt)
      B2[ftl][kt] = *reinterpret_cast<const bf16x8*>(
          &W2f[(((size_t)(w * 4 + ftl) * 4 + kt) * 64 + lane) * 8]);
  const int s = w >> 1;
  float blo[2], bhi[2];
#pragma unroll
  for (int p = 0; p < 2; ++p) {
    const int f_lo = (w & 1) * 64 + p * 32 + lcol;
    blo[p] = b2[3 * f_lo + 1 + s];
    bhi[p] = b2[3 * (f_lo + 16) + 1 + s];
  }
  __syncthreads();

#pragma unroll
  for (int sub = 0; sub < 2; ++sub) {
    bf16x8 ta[4];
#pragma unroll
    for (int kt = 0; kt < 4; ++kt) {
      const int row = sub * 16 + lcol;
      const int k0 = kt * 32 + hw * 8;
      const int byte = (row * 256 + k0 * 2) ^ ((row & 7) << 4);
      ta[kt] = *reinterpret_cast<const bf16x8*>((const char*)tS + byte);
    }
    f32x4 acc[4];
#pragma unroll
    for (int ftl = 0; ftl < 4; ++ftl) acc[ftl] = (f32x4){0.f, 0.f, 0.f, 0.f};
#pragma unroll
    for (int ftl = 0; ftl < 4; ++ftl)
#pragma unroll
      for (int kt = 0; kt < 4; ++kt)
        acc[ftl] = __builtin_amdgcn_mfma_f32_16x16x32_bf16(ta[kt], B2[ftl][kt], acc[ftl], 0, 0, 0);
#pragma unroll
    for (int p = 0; p < 2; ++p)
#pragma unroll
      for (int reg = 0; reg < 4; ++reg) {
        const int row = sub * 16 + hw * 4 + reg;
        const int gr = r0 + row;
        if (gr < BNA) {
          const float vlo = acc[2 * p][reg] + blo[p];
          const float vhi = acc[2 * p + 1][reg] + bhi[p];
          const unsigned int word = f2bf(vlo) | ((unsigned int)f2bf(vhi) << 16);
          phiP[(size_t)s * BNA * 64 + (size_t)gr * 64 + ((w & 1) * 2 + p) * 16 + lcol] = word;
        }
      }
  }
}

// Main fused kernel: 512 threads = 8 waves, 128-atom tiles, 2 barriers/tile.
// Wave w: split s=w>>2, f-block fb=w&3 (32 f-cols). G-gen threads compute
// their own distances from xyz (no dist phase / dl round-trip).
template <int ASPLIT>
__global__ __launch_bounds__(512, 4) void enc_main_kernel(
    const float* __restrict__ xyz, const float* __restrict__ cg_xyz,
    const unsigned short* __restrict__ Wff, const float* __restrict__ bf,
    const unsigned int* __restrict__ phiP,
    float* __restrict__ pH, float* __restrict__ pV,
    int NA, int NC, int BNC, int BNA) {
  __shared__ __bf16 Gl[8 * 4 * 64 * 8];  // 32 KB A-frag layout, 128 atoms
  __shared__ float ul[128 * 3];

  const int az = blockIdx.x;
  const int c = blockIdx.y;
  const int b = blockIdx.z;
  const int bc = b * NC + c;
  const int tid = threadIdx.x;
  const int lane = tid & 63;
  const int w = tid >> 6;        // 0..7
  const int s = w >> 2;          // 0: dH, 1: dV
  const int fb = w & 3;          // 32-col f-block
  const int hw = lane >> 4, lcol = lane & 15;

  const float cgx = cg_xyz[bc * 3 + 0];
  const float cgy = cg_xyz[bc * 3 + 1];
  const float cgz = cg_xyz[bc * 3 + 2];

  const int APA = (NA + ASPLIT - 1) / ASPLIT;
  const int a0 = az * APA;
  const int a_end = min(NA, a0 + APA);
  const int ntiles = (APA + 127) >> 7;

  // B fragments: ft = s*8 + fb*2 + ftl  (32 VGPR)
  bf16x8 Bf[2][4];
#pragma unroll
  for (int ftl = 0; ftl < 2; ++ftl)
#pragma unroll
    for (int kt = 0; kt < 4; ++kt)
      Bf[ftl][kt] = *reinterpret_cast<const bf16x8*>(
          &Wff[(((size_t)(s * 8 + fb * 2 + ftl) * 4 + kt) * 64 + lane) * 8]);

  float bfv[2];
#pragma unroll
  for (int ftl = 0; ftl < 2; ++ftl)
    bfv[ftl] = bf[3 * (fb * 32 + ftl * 16 + lcol) + 1 + s];

  const unsigned int* __restrict__ phiS = phiP + (size_t)s * BNA * 64;

  float dHp[2] = {0.f, 0.f};
  float dVp[2][3] = {};

  constexpr float DLT = 5.0f / 127.0f;
  constexpr float DLT2 = DLT * DLT;
  constexpr float E2C = 0.99690479f;  // exp(-2*DLT^2)

  // G-gen thread mapping: atom = tid&127, kt = tid>>7 (4 threads per atom).
  const int ga_a = tid & 127;
  const int ga_kt = tid >> 7;

  for (int t = 0; t < ntiles; ++t) {
    const int abase = a0 + t * 128;
    __syncthreads();  // prev-tile MFMA/epilogue done reading Gl/ul

    // unit vectors for this tile (threads 0..127, one atom each)
    if (tid < 128) {
      const int a = abase + tid;
      float ux = 0.f, uy = 0.f, uz = 0.f;
      if (a < a_end) {
        const float dx = xyz[(size_t)(b * NA + a) * 3 + 0] - cgx;
        const float dy = xyz[(size_t)(b * NA + a) * 3 + 1] - cgy;
        const float dz = xyz[(size_t)(b * NA + a) * 3 + 2] - cgz;
        const float d = sqrtf(dx * dx + dy * dy + dz * dz);
        const float inv = 1.0f / d;
        ux = dx * inv; uy = dy * inv; uz = dz * inv;
      }
      ul[tid * 3 + 0] = ux; ul[tid * 3 + 1] = uy; ul[tid * 3 + 2] = uz;
    }

    // phi prefetch: one packed u32 per (sub,reg)
    unsigned int pf[8][4];
#pragma unroll
    for (int sub = 0; sub < 8; ++sub)
#pragma unroll
      for (int reg = 0; reg < 4; ++reg) {
        const int a = abase + sub * 16 + hw * 4 + reg;
        pf[sub][reg] = (a < a_end)
            ? phiS[(size_t)(b * NA + a) * 64 + fb * 16 + lcol] : 0u;
      }

    // G generation: each thread owns (atom, kt) = 32 consecutive k via
    // exp recurrence (2 exp + 64 mul), self-computed distance.
    {
      const int a = abase + ga_a;
      float d;
      if (a < a_end) {
        const float dx = xyz[(size_t)(b * NA + a) * 3 + 0] - cgx;
        const float dy = xyz[(size_t)(b * NA + a) * 3 + 1] - cgy;
        const float dz = xyz[(size_t)(b * NA + a) * 3 + 2] - cgz;
        d = sqrtf(dx * dx + dy * dy + dz * dz);
      } else {
        d = 40.0f;  // exp(-(40-o)^2) == 0 for all offsets
      }
      const int kb = ga_kt * 32;
      const float d0 = d - (float)kb * DLT;
      float g = __expf(-d0 * d0);
      float mult = __expf(2.0f * DLT * d - (float)(2 * kb + 1) * DLT2);
      const int blk = ((ga_a >> 4) * 4 + ga_kt) * 64;
#pragma unroll
      for (int h2 = 0; h2 < 4; ++h2) {
        bf16x8 gv;
#pragma unroll
        for (int j = 0; j < 8; ++j) {
          gv[j] = (__bf16)g;
          g *= mult;
          mult *= E2C;
        }
        *reinterpret_cast<bf16x8*>(&Gl[(blk + (ga_a & 15) + 16 * h2) * 8]) = gv;
      }
    }
    __syncthreads();

    // MFMA + fused epilogue, per 16-atom sub-tile
#pragma unroll
    for (int sub = 0; sub < 8; ++sub) {
      bf16x8 ga[4];
#pragma unroll
      for (int kt = 0; kt < 4; ++kt)
        ga[kt] = *reinterpret_cast<const bf16x8*>(&Gl[((sub * 4 + kt) * 64 + lane) * 8]);
      f32x4 acc[2];
      acc[0] = (f32x4){0.f, 0.f, 0.f, 0.f};
      acc[1] = (f32x4){0.f, 0.f, 0.f, 0.f};
#pragma unroll
      for (int ftl = 0; ftl < 2; ++ftl)
#pragma unroll
        for (int kt = 0; kt < 4; ++kt)
          acc[ftl] = __builtin_amdgcn_mfma_f32_16x16x32_bf16(ga[kt], Bf[ftl][kt], acc[ftl], 0, 0, 0);
#pragma unroll
      for (int reg = 0; reg < 4; ++reg) {
        const int a_loc = sub * 16 + hw * 4 + reg;
        const unsigned int pw = pf[sub][reg];
        const float plo = bfw_lo(pw);
        const float phi_ = bfw_hi(pw);
        if (s == 0) {
          dHp[0] = fmaf(acc[0][reg] + bfv[0], plo, dHp[0]);
          dHp[1] = fmaf(acc[1][reg] + bfv[1], phi_, dHp[1]);
        } else {
          const float u0 = ul[a_loc * 3 + 0];
          const float u1 = ul[a_loc * 3 + 1];
          const float u2 = ul[a_loc * 3 + 2];
          const float t0 = (acc[0][reg] + bfv[0]) * plo;
          const float t1 = (acc[1][reg] + bfv[1]) * phi_;
          dVp[0][0] = fmaf(t0, u0, dVp[0][0]);
          dVp[0][1] = fmaf(t0, u1, dVp[0][1]);
          dVp[0][2] = fmaf(t0, u2, dVp[0][2]);
          dVp[1][0] = fmaf(t1, u0, dVp[1][0]);
          dVp[1][1] = fmaf(t1, u1, dVp[1][1]);
          dVp[1][2] = fmaf(t1, u2, dVp[1][2]);
        }
      }
    }
  }

  // reduce across hw groups (lanes sharing lcol) and store partials
#pragma unroll
  for (int ftl = 0; ftl < 2; ++ftl) {
    const int f = fb * 32 + ftl * 16 + lcol;
    if (s == 0) {
      float v = dHp[ftl];
      v += __shfl_xor(v, 16);
      v += __shfl_xor(v, 32);
      if (lane < 16)
        pH[(size_t)(az * BNC + bc) * FDIM + f] = v;
    } else {
#pragma unroll
      for (int x = 0; x < 3; ++x) {
        float v = dVp[ftl][x];
        v += __shfl_xor(v, 16);
        v += __shfl_xor(v, 32);
        if (lane < 16)
          pV[((size_t)(az * BNC + bc) * FDIM + f) * 3 + x] = v;
      }
    }
  }
}

template <int ASPLIT>
__global__ __launch_bounds__(FDIM) void reduce_kernel(
    const float* __restrict__ H, const float* __restrict__ pH, const float* __restrict__ pV,
    float* __restrict__ out, int BNC) {
  const int bc = blockIdx.x;
  const int f = threadIdx.x;
  float s = H[(size_t)bc * FDIM + f];
#pragma unroll
  for (int az = 0; az < ASPLIT; ++az) s += pH[(size_t)(az * BNC + bc) * FDIM + f];
  out[(size_t)bc * FDIM + f] = s;
  float* outV = out + (size_t)BNC * FDIM;
#pragma unroll
  for (int x = 0; x < 3; ++x) {
    float v = 0.f;
#pragma unroll
    for (int az = 0; az < ASPLIT; ++az) v += pV[((size_t)(az * BNC + bc) * FDIM + f) * 3 + x];
    outV[((size_t)bc * FDIM + f) * 3 + x] = v;
  }
}

extern "C" void kernel_launch(void* const* d_in, const int* in_sizes, int n_in,
                              void* d_out, int out_size, void* d_ws, size_t ws_size,
                              hipStream_t stream) {
  // inputs: 0 assign(unused), 1 h, 2 H, 3 cg_xyz, 4 xyz, 5 cg_adj(unused),
  //         6 Wf, 7 bf, 8 W1, 9 b1, 10 W2, 11 b2
  const float* h      = (const float*)d_in[1];
  const float* Hc     = (const float*)d_in[2];
  const float* cg_xyz = (const float*)d_in[3];
  const float* xyz    = (const float*)d_in[4];
  const float* Wf     = (const float*)d_in[6];
  const float* bf     = (const float*)d_in[7];
  const float* W1     = (const float*)d_in[8];
  const float* b1     = (const float*)d_in[9];
  const float* W2     = (const float*)d_in[10];
  const float* b2     = (const float*)d_in[11];

  const int BNC = in_sizes[2] / FDIM;      // B*NC
  const int NC  = in_sizes[5] / BNC;       // cg_adj = B*NC*NC
  const int B   = BNC / NC;
  const int NA  = in_sizes[0] / B;
  const int BNA = B * NA;
  constexpr int ASPLIT = 4;

  // Workspace layout (bytes; W1f = 8*4*64*8 ushorts = 32768 B)
  char* wsb = (char*)d_ws;
  unsigned short* W1f = (unsigned short*)wsb;                        // 32768 B
  unsigned short* Wff = (unsigned short*)(wsb + 32768);              // 65536 B
  unsigned short* W2f = (unsigned short*)(wsb + 32768 + 65536);      // 65536 B
  unsigned int*  phiP = (unsigned int*)(wsb + 32768 + 2 * 65536);    // 2*BNA*64*4 B
  float* pH = (float*)(wsb + 32768 + 2 * 65536 + (size_t)2 * BNA * 64 * 4);
  float* pV = pH + (size_t)ASPLIT * BNC * FDIM;

  pack_frag_kernel<<<dim3(16, 4, 3), 64, 0, stream>>>(W1, Wf, W2, W1f, Wff, W2f);
  phi_mfma_kernel<<<(BNA + 31) / 32, 256, 0, stream>>>(h, b1, b2, W1f, W2f, phiP, BNA);
  enc_main_kernel<ASPLIT><<<dim3(ASPLIT, NC, B), 512, 0, stream>>>(
      xyz, cg_xyz, Wff, bf, phiP, pH, pV, NA, NC, BNC, BNA);
  reduce_kernel<ASPLIT><<<BNC, FDIM, 0, stream>>>(Hc, pH, pV, (float*)d_out, BNC);
}

// Round 6
// 41.008 us; speedup vs baseline: 4.6858x; 1.0054x over previous
//
#include <hip/hip_runtime.h>
#include <cmath>

#define FDIM 128

typedef __attribute__((ext_vector_type(8))) __bf16 bf16x8;
typedef __attribute__((ext_vector_type(4))) float f32x4;

// RNE f32 -> bf16 bits (cold paths)
__device__ inline unsigned short f2bf(float x) {
  unsigned int u = __float_as_uint(x);
  return (unsigned short)((u + 0x7FFFu + ((u >> 16) & 1u)) >> 16);
}
__device__ inline float bfw_lo(unsigned int w) { return __uint_as_float(w << 16); }
__device__ inline float bfw_hi(unsigned int w) { return __uint_as_float(w & 0xFFFF0000u); }

// Pack all three weight mats into bf16 MFMA B-fragment layout [ft][kt][lane][j].
// z=0: W1 [128][128] (8 ft), z=1: Wf [128][384] used cols, z=2: W2 [128][384] used cols.
__global__ __launch_bounds__(64) void pack_frag_kernel(
    const float* __restrict__ W1, const float* __restrict__ Wf, const float* __restrict__ W2,
    unsigned short* __restrict__ W1f, unsigned short* __restrict__ Wff,
    unsigned short* __restrict__ W2f) {
  const int ft = blockIdx.x, kt = blockIdx.y, z = blockIdx.z;
  const int lane = threadIdx.x;
  const float* W;
  unsigned short* out;
  int col, stride;
  if (z == 0) {
    if (ft >= 8) return;
    W = W1; out = W1f; col = ft * 16 + (lane & 15); stride = 128;
  } else {
    W = (z == 1) ? Wf : W2;
    out = (z == 1) ? Wff : W2f;
    col = 3 * ((ft & 7) * 16 + (lane & 15)) + 1 + (ft >> 3);
    stride = 384;
  }
  unsigned short g[8];
#pragma unroll
  for (int j = 0; j < 8; ++j) {
    const int k = kt * 32 + ((lane >> 4) << 3) + j;
    g[j] = f2bf(W[(size_t)k * stride + col]);
  }
  uint4 u;
  u.x = g[0] | ((unsigned int)g[1] << 16);
  u.y = g[2] | ((unsigned int)g[3] << 16);
  u.z = g[4] | ((unsigned int)g[5] << 16);
  u.w = g[6] | ((unsigned int)g[7] << 16);
  *(uint4*)&out[((size_t)(ft * 4 + kt) * 64 + lane) * 8] = u;
}

// phi = silu(h@W1+b1)@W2+b2 (used cols only), via two MFMA passes.
// 16 rows per block (188 blocks -> better CU coverage), 4 waves.
// Output: phiP[s][row][q] u32 packing (phi[fb*32+lcol], phi[fb*32+16+lcol]).
__global__ __launch_bounds__(256) void phi_mfma_kernel(
    const float* __restrict__ h, const float* __restrict__ b1, const float* __restrict__ b2,
    const unsigned short* __restrict__ W1f, const unsigned short* __restrict__ W2f,
    unsigned int* __restrict__ phiP, int BNA) {
  __shared__ __bf16 hA[4 * 64 * 8];           // 4 KB: h tile (16 rows), A-frag layout
  __shared__ unsigned short tS[16 * 128];     // 4 KB: t tile, swizzled row-major
  const int tid = threadIdx.x;
  const int lane = tid & 63;
  const int w = tid >> 6;       // 0..3
  const int hw = lane >> 4, lcol = lane & 15;
  const int r0 = blockIdx.x * 16;

  // stage h -> A-frag bf16 (one b128 group per thread)
  {
    const int gl = tid & 63;
    const int kt = tid >> 6;
    const int row = gl & 15;
    const int k0 = kt * 32 + ((gl >> 4) << 3);
    const int gr = r0 + row;
    bf16x8 v;
    if (gr < BNA) {
      const float4 f0 = *(const float4*)&h[(size_t)gr * FDIM + k0];
      const float4 f1 = *(const float4*)&h[(size_t)gr * FDIM + k0 + 4];
      v[0] = (__bf16)f0.x; v[1] = (__bf16)f0.y; v[2] = (__bf16)f0.z; v[3] = (__bf16)f0.w;
      v[4] = (__bf16)f1.x; v[5] = (__bf16)f1.y; v[6] = (__bf16)f1.z; v[7] = (__bf16)f1.w;
    } else {
#pragma unroll
      for (int j = 0; j < 8; ++j) v[j] = (__bf16)0.0f;
    }
    *reinterpret_cast<bf16x8*>(&hA[tid * 8]) = v;
  }

  // pass1 B-frags (W1): wave w -> f-cols [w*32, w*32+32)
  bf16x8 B1[2][4];
#pragma unroll
  for (int ftl = 0; ftl < 2; ++ftl)
#pragma unroll
    for (int kt = 0; kt < 4; ++kt)
      B1[ftl][kt] = *reinterpret_cast<const bf16x8*>(
          &W1f[(((size_t)(w * 2 + ftl) * 4 + kt) * 64 + lane) * 8]);
  float b1v[2];
#pragma unroll
  for (int ftl = 0; ftl < 2; ++ftl) b1v[ftl] = b1[w * 32 + ftl * 16 + lcol];
  __syncthreads();

  {
    bf16x8 ga[4];
#pragma unroll
    for (int kt = 0; kt < 4; ++kt)
      ga[kt] = *reinterpret_cast<const bf16x8*>(&hA[(kt * 64 + lane) * 8]);
    f32x4 acc[2];
    acc[0] = (f32x4){0.f, 0.f, 0.f, 0.f};
    acc[1] = (f32x4){0.f, 0.f, 0.f, 0.f};
#pragma unroll
    for (int ftl = 0; ftl < 2; ++ftl)
#pragma unroll
      for (int kt = 0; kt < 4; ++kt)
        acc[ftl] = __builtin_amdgcn_mfma_f32_16x16x32_bf16(ga[kt], B1[ftl][kt], acc[ftl], 0, 0, 0);
#pragma unroll
    for (int ftl = 0; ftl < 2; ++ftl)
#pragma unroll
      for (int reg = 0; reg < 4; ++reg) {
        const int row = hw * 4 + reg;
        const int fcol = w * 32 + ftl * 16 + lcol;
        const float x = acc[ftl][reg] + b1v[ftl];
        const float t = x / (1.0f + __expf(-x));
        const int byte = (row * 256 + fcol * 2) ^ ((row & 7) << 4);
        *(unsigned short*)((char*)tS + byte) = f2bf(t);
      }
  }

  // pass2 B-frags (W2 used cols): wave w -> 64 of 256 f'-cols
  bf16x8 B2[4][4];
#pragma unroll
  for (int ftl = 0; ftl < 4; ++ftl)
#pragma unroll
    for (int kt = 0; kt < 4; ++kt)
      B2[ftl][kt] = *reinterpret_cast<const bf16x8*>(
          &W2f[(((size_t)(w * 4 + ftl) * 4 + kt) * 64 + lane) * 8]);
  const int s = w >> 1;
  float blo[2], bhi[2];
#pragma unroll
  for (int p = 0; p < 2; ++p) {
    const int f_lo = (w & 1) * 64 + p * 32 + lcol;
    blo[p] = b2[3 * f_lo + 1 + s];
    bhi[p] = b2[3 * (f_lo + 16) + 1 + s];
  }
  __syncthreads();

  {
    bf16x8 ta[4];
#pragma unroll
    for (int kt = 0; kt < 4; ++kt) {
      const int row = lcol;
      const int k0 = kt * 32 + hw * 8;
      const int byte = (row * 256 + k0 * 2) ^ ((row & 7) << 4);
      ta[kt] = *reinterpret_cast<const bf16x8*>((const char*)tS + byte);
    }
    f32x4 acc[4];
#pragma unroll
    for (int ftl = 0; ftl < 4; ++ftl) acc[ftl] = (f32x4){0.f, 0.f, 0.f, 0.f};
#pragma unroll
    for (int ftl = 0; ftl < 4; ++ftl)
#pragma unroll
      for (int kt = 0; kt < 4; ++kt)
        acc[ftl] = __builtin_amdgcn_mfma_f32_16x16x32_bf16(ta[kt], B2[ftl][kt], acc[ftl], 0, 0, 0);
#pragma unroll
    for (int p = 0; p < 2; ++p)
#pragma unroll
      for (int reg = 0; reg < 4; ++reg) {
        const int row = hw * 4 + reg;
        const int gr = r0 + row;
        if (gr < BNA) {
          const float vlo = acc[2 * p][reg] + blo[p];
          const float vhi = acc[2 * p + 1][reg] + bhi[p];
          const unsigned int word = f2bf(vlo) | ((unsigned int)f2bf(vhi) << 16);
          phiP[(size_t)s * BNA * 64 + (size_t)gr * 64 + ((w & 1) * 2 + p) * 16 + lcol] = word;
        }
      }
  }
}

// ---------- enc_main helpers (64-atom half-tiles, double-buffered) ----------

#define DLT  (5.0f / 127.0f)
#define DLT2 (DLT * DLT)
#define E2C  0.99690479f  /* exp(-2*DLT^2) */

// G-gen for one 64-atom half: 512 threads, 8 threads/atom, 16 k each
// (two depth-8 exp-recurrence chains). Also writes unit vectors (kg==0).
__device__ __forceinline__ void gen_half(
    const float* __restrict__ xyz, size_t arow, int habase, int a_end,
    float cgx, float cgy, float cgz, __bf16* GlH, float* ulH, int tid) {
  const int a_loc = tid & 63;
  const int kg = tid >> 6;  // 0..7, k0 = kg*16
  const int a = habase + a_loc;
  float d, ux = 0.f, uy = 0.f, uz = 0.f;
  if (a < a_end) {
    const float dx = xyz[(arow + a) * 3 + 0] - cgx;
    const float dy = xyz[(arow + a) * 3 + 1] - cgy;
    const float dz = xyz[(arow + a) * 3 + 2] - cgz;
    d = sqrtf(dx * dx + dy * dy + dz * dz);
    const float inv = 1.0f / d;
    ux = dx * inv; uy = dy * inv; uz = dz * inv;
  } else {
    d = 40.0f;  // exp(-(40-o)^2) == 0 for all offsets
  }
  if (kg == 0) {
    ulH[a_loc * 3 + 0] = ux; ulH[a_loc * 3 + 1] = uy; ulH[a_loc * 3 + 2] = uz;
  }
  const int kt = kg >> 1, h2 = kg & 1;
  const int sub = a_loc >> 4;
#pragma unroll
  for (int c = 0; c < 2; ++c) {
    const int kb = kg * 16 + c * 8;
    const float d0 = d - (float)kb * DLT;
    float g = __expf(-d0 * d0);
    float r = __expf(2.0f * DLT * d - (float)(2 * kb + 1) * DLT2);
    bf16x8 gv;
#pragma unroll
    for (int j = 0; j < 8; ++j) {
      gv[j] = (__bf16)g;
      g *= r;
      r *= E2C;
    }
    const int lane = (2 * h2 + c) * 16 + (a_loc & 15);
    *reinterpret_cast<bf16x8*>(&GlH[((sub * 4 + kt) * 64 + lane) * 8]) = gv;
  }
}

__device__ __forceinline__ void load_pf(
    unsigned int (&pf)[4][4], const unsigned int* __restrict__ phiS,
    size_t arow, int habase, int a_end, int qoff, int hw) {
#pragma unroll
  for (int sub = 0; sub < 4; ++sub)
#pragma unroll
    for (int reg = 0; reg < 4; ++reg) {
      const int a = habase + sub * 16 + hw * 4 + reg;
      pf[sub][reg] = (a < a_end) ? phiS[(arow + a) * 64 + qoff] : 0u;
    }
}

// 16 MFMA per sub-pair... per half: 4 subs x 2 ftl x 4 kt = 32 MFMA + epilogue.
__device__ __forceinline__ void mfma_epi(
    const __bf16* GlH, const float* ulH, const unsigned int (&pf)[4][4],
    const bf16x8 (&Bf)[2][4], const float (&bfv)[2],
    int lane, int hw, int s, float (&dHp)[2], float (&dVp)[2][3]) {
#pragma unroll
  for (int sub = 0; sub < 4; ++sub) {
    bf16x8 ga[4];
#pragma unroll
    for (int kt = 0; kt < 4; ++kt)
      ga[kt] = *reinterpret_cast<const bf16x8*>(&GlH[((sub * 4 + kt) * 64 + lane) * 8]);
    f32x4 acc[2];
    acc[0] = (f32x4){0.f, 0.f, 0.f, 0.f};
    acc[1] = (f32x4){0.f, 0.f, 0.f, 0.f};
    __builtin_amdgcn_s_setprio(1);
#pragma unroll
    for (int ftl = 0; ftl < 2; ++ftl)
#pragma unroll
      for (int kt = 0; kt < 4; ++kt)
        acc[ftl] = __builtin_amdgcn_mfma_f32_16x16x32_bf16(ga[kt], Bf[ftl][kt], acc[ftl], 0, 0, 0);
    __builtin_amdgcn_s_setprio(0);
#pragma unroll
    for (int reg = 0; reg < 4; ++reg) {
      const int a_loc = sub * 16 + hw * 4 + reg;
      const unsigned int pw = pf[sub][reg];
      const float plo = bfw_lo(pw);
      const float phi_ = bfw_hi(pw);
      if (s == 0) {
        dHp[0] = fmaf(acc[0][reg] + bfv[0], plo, dHp[0]);
        dHp[1] = fmaf(acc[1][reg] + bfv[1], phi_, dHp[1]);
      } else {
        const float u0 = ulH[a_loc * 3 + 0];
        const float u1 = ulH[a_loc * 3 + 1];
        const float u2 = ulH[a_loc * 3 + 2];
        const float t0 = (acc[0][reg] + bfv[0]) * plo;
        const float t1 = (acc[1][reg] + bfv[1]) * phi_;
        dVp[0][0] = fmaf(t0, u0, dVp[0][0]);
        dVp[0][1] = fmaf(t0, u1, dVp[0][1]);
        dVp[0][2] = fmaf(t0, u2, dVp[0][2]);
        dVp[1][0] = fmaf(t1, u0, dVp[1][0]);
        dVp[1][1] = fmaf(t1, u1, dVp[1][1]);
        dVp[1][2] = fmaf(t1, u2, dVp[1][2]);
      }
    }
  }
}

// Main fused kernel: 512 threads = 8 waves. Wave w: split s=w>>2, f-block
// fb=w&3 (32 f-cols). Software-pipelined 64-atom half-tiles: gen(next half)
// overlaps MFMA+epilogue(cur half); one barrier per half.
template <int ASPLIT>
__global__ __launch_bounds__(512, 4) void enc_main_kernel(
    const float* __restrict__ xyz, const float* __restrict__ cg_xyz,
    const unsigned short* __restrict__ Wff, const float* __restrict__ bf,
    const unsigned int* __restrict__ phiP,
    float* __restrict__ pH, float* __restrict__ pV,
    int NA, int NC, int BNC, int BNA) {
  __shared__ __bf16 Gl[2][4 * 4 * 64 * 8];  // 2 x 16 KB A-frag layout (64 atoms)
  __shared__ float ul[2][64 * 3];

  const int az = blockIdx.x;
  const int c = blockIdx.y;
  const int b = blockIdx.z;
  const int bc = b * NC + c;
  const int tid = threadIdx.x;
  const int lane = tid & 63;
  const int w = tid >> 6;        // 0..7
  const int s = w >> 2;          // 0: dH, 1: dV
  const int fb = w & 3;          // 32-col f-block
  const int hw = lane >> 4, lcol = lane & 15;
  const size_t arow = (size_t)b * NA;

  const float cgx = cg_xyz[bc * 3 + 0];
  const float cgy = cg_xyz[bc * 3 + 1];
  const float cgz = cg_xyz[bc * 3 + 2];

  const int APA = (NA + ASPLIT - 1) / ASPLIT;
  const int a0 = az * APA;
  const int a_end = min(NA, a0 + APA);
  const int H = (a_end > a0) ? ((a_end - a0 + 63) >> 6) : 0;

  // B fragments: ft = s*8 + fb*2 + ftl  (32 VGPR)
  bf16x8 Bf[2][4];
#pragma unroll
  for (int ftl = 0; ftl < 2; ++ftl)
#pragma unroll
    for (int kt = 0; kt < 4; ++kt)
      Bf[ftl][kt] = *reinterpret_cast<const bf16x8*>(
          &Wff[(((size_t)(s * 8 + fb * 2 + ftl) * 4 + kt) * 64 + lane) * 8]);

  float bfv[2];
#pragma unroll
  for (int ftl = 0; ftl < 2; ++ftl)
    bfv[ftl] = bf[3 * (fb * 32 + ftl * 16 + lcol) + 1 + s];

  const unsigned int* __restrict__ phiS = phiP + (size_t)s * BNA * 64;
  const int qoff = fb * 16 + lcol;

  float dHp[2] = {0.f, 0.f};
  float dVp[2][3] = {};

  if (H > 0) {
    gen_half(xyz, arow, a0, a_end, cgx, cgy, cgz, Gl[0], ul[0], tid);
  }
  __syncthreads();

  for (int base = 0; base < H; base += 2) {
    // parity 0: current = buf0, next -> buf1
    {
      unsigned int pf[4][4];
      load_pf(pf, phiS, arow, a0 + base * 64, a_end, qoff, hw);
      if (base + 1 < H)
        gen_half(xyz, arow, a0 + (base + 1) * 64, a_end, cgx, cgy, cgz, Gl[1], ul[1], tid);
      mfma_epi(Gl[0], ul[0], pf, Bf, bfv, lane, hw, s, dHp, dVp);
      __syncthreads();
    }
    // parity 1: current = buf1, next -> buf0
    if (base + 1 < H) {
      unsigned int pf[4][4];
      load_pf(pf, phiS, arow, a0 + (base + 1) * 64, a_end, qoff, hw);
      if (base + 2 < H)
        gen_half(xyz, arow, a0 + (base + 2) * 64, a_end, cgx, cgy, cgz, Gl[0], ul[0], tid);
      mfma_epi(Gl[1], ul[1], pf, Bf, bfv, lane, hw, s, dHp, dVp);
      __syncthreads();
    }
  }

  // reduce across hw groups (lanes sharing lcol) and store partials
#pragma unroll
  for (int ftl = 0; ftl < 2; ++ftl) {
    const int f = fb * 32 + ftl * 16 + lcol;
    if (s == 0) {
      float v = dHp[ftl];
      v += __shfl_xor(v, 16);
      v += __shfl_xor(v, 32);
      if (lane < 16)
        pH[(size_t)(az * BNC + bc) * FDIM + f] = v;
    } else {
#pragma unroll
      for (int x = 0; x < 3; ++x) {
        float v = dVp[ftl][x];
        v += __shfl_xor(v, 16);
        v += __shfl_xor(v, 32);
        if (lane < 16)
          pV[((size_t)(az * BNC + bc) * FDIM + f) * 3 + x] = v;
      }
    }
  }
}

template <int ASPLIT>
__global__ __launch_bounds__(FDIM) void reduce_kernel(
    const float* __restrict__ H, const float* __restrict__ pH, const float* __restrict__ pV,
    float* __restrict__ out, int BNC) {
  const int bc = blockIdx.x;
  const int f = threadIdx.x;
  float s = H[(size_t)bc * FDIM + f];
#pragma unroll
  for (int az = 0; az < ASPLIT; ++az) s += pH[(size_t)(az * BNC + bc) * FDIM + f];
  out[(size_t)bc * FDIM + f] = s;
  float* outV = out + (size_t)BNC * FDIM;
#pragma unroll
  for (int x = 0; x < 3; ++x) {
    float v = 0.f;
#pragma unroll
    for (int az = 0; az < ASPLIT; ++az) v += pV[((size_t)(az * BNC + bc) * FDIM + f) * 3 + x];
    outV[((size_t)bc * FDIM + f) * 3 + x] = v;
  }
}

extern "C" void kernel_launch(void* const* d_in, const int* in_sizes, int n_in,
                              void* d_out, int out_size, void* d_ws, size_t ws_size,
                              hipStream_t stream) {
  // inputs: 0 assign(unused), 1 h, 2 H, 3 cg_xyz, 4 xyz, 5 cg_adj(unused),
  //         6 Wf, 7 bf, 8 W1, 9 b1, 10 W2, 11 b2
  const float* h      = (const float*)d_in[1];
  const float* Hc     = (const float*)d_in[2];
  const float* cg_xyz = (const float*)d_in[3];
  const float* xyz    = (const float*)d_in[4];
  const float* Wf     = (const float*)d_in[6];
  const float* bf     = (const float*)d_in[7];
  const float* W1     = (const float*)d_in[8];
  const float* b1     = (const float*)d_in[9];
  const float* W2     = (const float*)d_in[10];
  const float* b2     = (const float*)d_in[11];

  const int BNC = in_sizes[2] / FDIM;      // B*NC
  const int NC  = in_sizes[5] / BNC;       // cg_adj = B*NC*NC
  const int B   = BNC / NC;
  const int NA  = in_sizes[0] / B;
  const int BNA = B * NA;
  constexpr int ASPLIT = 4;

  // Workspace layout (bytes; W1f = 8*4*64*8 ushorts = 32768 B)
  char* wsb = (char*)d_ws;
  unsigned short* W1f = (unsigned short*)wsb;                        // 32768 B
  unsigned short* Wff = (unsigned short*)(wsb + 32768);              // 65536 B
  unsigned short* W2f = (unsigned short*)(wsb + 32768 + 65536);      // 65536 B
  unsigned int*  phiP = (unsigned int*)(wsb + 32768 + 2 * 65536);    // 2*BNA*64*4 B
  float* pH = (float*)(wsb + 32768 + 2 * 65536 + (size_t)2 * BNA * 64 * 4);
  float* pV = pH + (size_t)ASPLIT * BNC * FDIM;

  pack_frag_kernel<<<dim3(16, 4, 3), 64, 0, stream>>>(W1, Wf, W2, W1f, Wff, W2f);
  phi_mfma_kernel<<<(BNA + 15) / 16, 256, 0, stream>>>(h, b1, b2, W1f, W2f, phiP, BNA);
  enc_main_kernel<ASPLIT><<<dim3(ASPLIT, NC, B), 512, 0, stream>>>(
      xyz, cg_xyz, Wff, bf, phiP, pH, pV, NA, NC, BNC, BNA);
  reduce_kernel<ASPLIT><<<BNC, FDIM, 0, stream>>>(Hc, pH, pV, (float*)d_out, BNC);
}